// Round 8
// baseline (141.558 us; speedup 1.0000x reference)
//
#include <hip/hip_runtime.h>
#include <math.h>

#define OUT_DIM 8192
#define C_DIM   512
#define B_DIM   16
#define HW      196

typedef __attribute__((ext_vector_type(8))) short bf16x8;
typedef __attribute__((ext_vector_type(4))) float f32x4;

// Packed fragment-native layout, per plane (hi or lo), 8 kb-chunks (kb7 = zeros):
//   idx(b, rb, kb, lk, r, e) = ((((b*32 + rb)*8 + kb)*4 + lk)*128 + r*8 + e
// A wave's 16x32 fragment at (rb,kb) = contiguous 1KB; lane l reads 16B at l*16.
// Plane size: 16*32*8*512 ushorts = 4 MB.

// ---------------------------------------------------------------------------
// K1 prep: [0,1024) sketch extraction; [1024,1536) pack x -> fragment planes.
// ---------------------------------------------------------------------------
__global__ __launch_bounds__(256) void prep(
    const float* __restrict__ x,
    const float* __restrict__ S1, const float* __restrict__ S2,
    int* __restrict__ h1, float* __restrict__ s1,
    int* __restrict__ h2, float* __restrict__ s2,
    unsigned short* __restrict__ PH, unsigned short* __restrict__ PLo)
{
    const int bid = blockIdx.x;
    const int t = threadIdx.x;

    if (bid < 1024) {
        int row = bid & 511;
        const float* S = (bid < 512) ? S1 : S2;
        int* h = (bid < 512) ? h1 : h2;
        float* s = (bid < 512) ? s1 : s2;
        const float4* p = (const float4*)(S + (size_t)row * OUT_DIM);
#pragma unroll
        for (int m = 0; m < 8; ++m) {
            int q = t + m * 256;
            float4 v = p[q];
            int base = q * 4;
            if (v.x != 0.f) { h[row] = base + 0; s[row] = v.x; }
            if (v.y != 0.f) { h[row] = base + 1; s[row] = v.y; }
            if (v.z != 0.f) { h[row] = base + 2; s[row] = v.z; }
            if (v.w != 0.f) { h[row] = base + 3; s[row] = v.w; }
        }
        return;
    }

    // pack: one block per (b, rb) = 16 rows of one batch
    const int u = bid - 1024;             // 0..511
    const int b = u >> 5, rb = u & 31;
    __shared__ float xs[16 * HW];
    const float* src = x + ((size_t)b * C_DIM + rb * 16) * HW;
#pragma unroll
    for (int i = 0; i < 13; ++i) {
        int idx = t + i * 256;
        if (idx < 16 * HW) xs[idx] = src[idx];
    }
    __syncthreads();

    const int r = t & 15, u0 = t >> 4;
#pragma unroll
    for (int p = 0; p < 2; ++p) {
        int unit = u0 + p * 16;           // 0..31 (units 28..31 -> zeros, kb7 pad)
        bf16x8 hv, lv;
#pragma unroll
        for (int e = 0; e < 8; ++e) {
            int k = unit * 8 + e;
            float v = (k < HW) ? xs[r * HW + k] : 0.f;
            unsigned int uv = __float_as_uint(v);
            unsigned short hi = (unsigned short)(uv >> 16);
            float hif = __uint_as_float(((unsigned int)hi) << 16);
            hv[e] = (short)hi;
            lv[e] = (short)(__float_as_uint(v - hif) >> 16);
        }
        int kb = unit >> 2, lk = unit & 3;
        size_t base = ((((size_t)b * 32 + rb) * 8 + kb) * 4 + lk) * 128 + r * 8;
        *(bf16x8*)(PH + base) = hv;
        *(bf16x8*)(PLo + base) = lv;
    }
}

// ---------------------------------------------------------------------------
// K2: Gram via MFMA, fragments direct from L2-resident packed planes.
// IDENTICAL to R7 except the scatter uses unsafeAtomicAdd (native ds_add_f32)
// instead of atomicAdd (CAS loop) — the single-variable A/B experiment.
// ---------------------------------------------------------------------------
__global__ __launch_bounds__(512, 2) void gram_mfma(
    const unsigned short* __restrict__ PH, const unsigned short* __restrict__ PLo,
    const int* __restrict__ h1, const float* __restrict__ s1,
    const int* __restrict__ h2, const float* __restrict__ s2,
    float* __restrict__ partials)
{
    __shared__ float bins[OUT_DIM];       // 32 KB

    const int bid = blockIdx.x;
    const int xcd = bid & 7;
    const int idx = bid >> 3;             // 0..31
    const int b   = xcd + 8 * (idx & 1);
    const int tile = idx >> 1;            // 0..15
    const int c1b = (tile >> 2) * 128, c2b = (tile & 3) * 128;

    const int t = threadIdx.x;
    const int l = t & 63, w = t >> 6;
    const int half = w >> 2;              // K-half: kb0 = half*4
    const int wr = (w >> 1) & 1, wc = w & 1;

    for (int mm = t; mm < OUT_DIM; mm += 512) bins[mm] = 0.f;

    // frag(rb, kb) base: ((b*32+rb)*8 + kb)*512 + l*8
    const int arb = b * 32 + (c1b >> 4) + wr * 4;   // + m
    const int brb = b * 32 + (c2b >> 4) + wc * 4;   // + n
    const int loff = l * 8;
    const int kb0 = half * 4;

#define FRAG(P, rb, kb) (*(const bf16x8*)((P) + ((size_t)((rb) * 8 + (kb)) * 512) + loff))

    f32x4 acc[4][4];
#pragma unroll
    for (int m = 0; m < 4; ++m)
#pragma unroll
        for (int n = 0; n < 4; ++n) acc[m][n] = (f32x4){0.f, 0.f, 0.f, 0.f};

    bf16x8 ah[2][4], al[2][4], bh[2][4], bl[2][4];
#pragma unroll
    for (int m = 0; m < 4; ++m) {
        ah[0][m] = FRAG(PH,  arb + m, kb0);
        al[0][m] = FRAG(PLo, arb + m, kb0);
        bh[0][m] = FRAG(PH,  brb + m, kb0);
        bl[0][m] = FRAG(PLo, brb + m, kb0);
    }

#pragma unroll
    for (int i = 0; i < 4; ++i) {
        const int cur = i & 1, nxt = cur ^ 1;
        if (i < 3) {
            const int kn = kb0 + i + 1;
#pragma unroll
            for (int m = 0; m < 4; ++m) {
                ah[nxt][m] = FRAG(PH,  arb + m, kn);
                al[nxt][m] = FRAG(PLo, arb + m, kn);
                bh[nxt][m] = FRAG(PH,  brb + m, kn);
                bl[nxt][m] = FRAG(PLo, brb + m, kn);
            }
        }
#pragma unroll
        for (int m = 0; m < 4; ++m)
#pragma unroll
            for (int n = 0; n < 4; ++n) {
                acc[m][n] = __builtin_amdgcn_mfma_f32_16x16x32_bf16(ah[cur][m], bh[cur][n], acc[m][n], 0, 0, 0);
                acc[m][n] = __builtin_amdgcn_mfma_f32_16x16x32_bf16(ah[cur][m], bl[cur][n], acc[m][n], 0, 0, 0);
                acc[m][n] = __builtin_amdgcn_mfma_f32_16x16x32_bf16(al[cur][m], bh[cur][n], acc[m][n], 0, 0, 0);
            }
    }
#undef FRAG

    // C/D layout (verified R3-R7): c2 = col = lane&15, c1 = row = (lane>>4)*4 + reg
    const int lrow = l & 15, lk = l >> 4;
    int   hh1[4][4]; float sv1[4][4];
    int   hh2[4];    float sv2[4];
#pragma unroll
    for (int m = 0; m < 4; ++m)
#pragma unroll
        for (int r = 0; r < 4; ++r) {
            int c1 = c1b + wr * 64 + m * 16 + lk * 4 + r;
            hh1[m][r] = h1[c1]; sv1[m][r] = s1[c1];
        }
#pragma unroll
    for (int n = 0; n < 4; ++n) {
        int c2 = c2b + wc * 64 + n * 16 + lrow;
        hh2[n] = h2[c2]; sv2[n] = s2[c2];
    }

    __syncthreads();                      // bins zeroed; all frag loads done
#pragma unroll
    for (int m = 0; m < 4; ++m)
#pragma unroll
        for (int n = 0; n < 4; ++n)
#pragma unroll
            for (int r = 0; r < 4; ++r) {
                int bin = (hh1[m][r] + hh2[n]) & (OUT_DIM - 1);
                unsafeAtomicAdd(&bins[bin], acc[m][n][r] * sv1[m][r] * sv2[n]);
            }
    __syncthreads();

    float* outp = partials + (size_t)(b * 16 + tile) * OUT_DIM;
    for (int mm = t; mm < OUT_DIM; mm += 512) outp[mm] = bins[mm];
}

// ---------------------------------------------------------------------------
// K3 fin: one block per batch (1024 thr). Reduce 16 slabs, *8192, signed
// sqrt, block-reduce L2 norm, normalize, write out.
// ---------------------------------------------------------------------------
__global__ __launch_bounds__(1024) void fin(
    const float* __restrict__ partials, float* __restrict__ out)
{
    const int b = blockIdx.x, t = threadIdx.x;
    const float* pb = partials + (size_t)b * 16 * OUT_DIM;
    float v[8];
    float sq = 0.f;
#pragma unroll
    for (int i = 0; i < 8; ++i) {
        int k = t + i * 1024;
        float a = 0.f;
#pragma unroll
        for (int tl = 0; tl < 16; ++tl)
            a += pb[tl * OUT_DIM + k];
        a *= (float)OUT_DIM;
        float sg = (a > 0.f) ? 1.f : ((a < 0.f) ? -1.f : 0.f);
        v[i] = sg * sqrtf(fabsf(a) + 1e-5f);
        sq += fabsf(a) + 1e-5f;           // = v[i]^2
    }
#pragma unroll
    for (int off = 32; off; off >>= 1) sq += __shfl_down(sq, off, 64);
    __shared__ float red[16];
    if ((t & 63) == 0) red[t >> 6] = sq;
    __syncthreads();
    float tot = 0.f;
#pragma unroll
    for (int i = 0; i < 16; ++i) tot += red[i];
    float inv = 1.f / fmaxf(sqrtf(tot), 1e-12f);
#pragma unroll
    for (int i = 0; i < 8; ++i)
        out[(size_t)b * OUT_DIM + t + i * 1024] = v[i] * inv;
}

// ---------------------------------------------------------------------------
extern "C" void kernel_launch(void* const* d_in, const int* in_sizes, int n_in,
                              void* d_out, int out_size, void* d_ws, size_t ws_size,
                              hipStream_t stream) {
    const float* x   = (const float*)d_in[0];
    const float* sk1 = (const float*)d_in[1];
    const float* sk2 = (const float*)d_in[2];

    char* ws = (char*)d_ws;
    int*   h1 = (int*)(ws);                              //       0 + 2048
    float* s1 = (float*)(ws + 2048);                     //    2048 + 2048
    int*   h2 = (int*)(ws + 4096);                       //    4096 + 2048
    float* s2 = (float*)(ws + 6144);                     //    6144 + 2048
    float* partials = (float*)(ws + 8192);               // [256][8192] f32 = 8388608
    unsigned short* PH  = (unsigned short*)(ws + 8396800);   // 4 MB (16*32*8*512 u16)
    unsigned short* PLo = (unsigned short*)(ws + 12591104);  // 4 MB -> 16785408 total

    prep<<<1536, 256, 0, stream>>>(x, sk1, sk2, h1, s1, h2, s2, PH, PLo);
    gram_mfma<<<256, 512, 0, stream>>>(PH, PLo, h1, s1, h2, s2, partials);
    fin<<<B_DIM, 1024, 0, stream>>>(partials, (float*)d_out);
}

// Round 9
// 139.599 us; speedup vs baseline: 1.0140x; 1.0140x over previous
//
#include <hip/hip_runtime.h>
#include <math.h>

#define OUT_DIM 8192
#define C_DIM   512
#define B_DIM   16
#define HW      196

typedef __attribute__((ext_vector_type(8))) short bf16x8;
typedef __attribute__((ext_vector_type(4))) float f32x4;

// Packed fragment-native layout, per plane (hi or lo), 8 kb-chunks (kb7 = zeros):
//   idx(b, rb, kb, lk, r, e) = ((((b*32 + rb)*8 + kb)*4 + lk)*128 + r*8 + e
// A wave's 16x32 fragment at (rb,kb) = contiguous 1KB; lane l reads 16B at l*16.

// ---------------------------------------------------------------------------
// K1 prep: [0,1024) sketch extraction; [1024,1536) pack x -> fragment planes.
// ---------------------------------------------------------------------------
__global__ __launch_bounds__(256) void prep(
    const float* __restrict__ x,
    const float* __restrict__ S1, const float* __restrict__ S2,
    int* __restrict__ h1, float* __restrict__ s1,
    int* __restrict__ h2, float* __restrict__ s2,
    unsigned short* __restrict__ PH, unsigned short* __restrict__ PLo)
{
    const int bid = blockIdx.x;
    const int t = threadIdx.x;

    if (bid < 1024) {
        int row = bid & 511;
        const float* S = (bid < 512) ? S1 : S2;
        int* h = (bid < 512) ? h1 : h2;
        float* s = (bid < 512) ? s1 : s2;
        const float4* p = (const float4*)(S + (size_t)row * OUT_DIM);
#pragma unroll
        for (int m = 0; m < 8; ++m) {
            int q = t + m * 256;
            float4 v = p[q];
            int base = q * 4;
            if (v.x != 0.f) { h[row] = base + 0; s[row] = v.x; }
            if (v.y != 0.f) { h[row] = base + 1; s[row] = v.y; }
            if (v.z != 0.f) { h[row] = base + 2; s[row] = v.z; }
            if (v.w != 0.f) { h[row] = base + 3; s[row] = v.w; }
        }
        return;
    }

    const int u = bid - 1024;             // 0..511
    const int b = u >> 5, rb = u & 31;
    __shared__ float xs[16 * HW];
    const float* src = x + ((size_t)b * C_DIM + rb * 16) * HW;
#pragma unroll
    for (int i = 0; i < 13; ++i) {
        int idx = t + i * 256;
        if (idx < 16 * HW) xs[idx] = src[idx];
    }
    __syncthreads();

    const int r = t & 15, u0 = t >> 4;
#pragma unroll
    for (int p = 0; p < 2; ++p) {
        int unit = u0 + p * 16;           // 0..31 (units 28..31 -> zeros, kb7 pad)
        bf16x8 hv, lv;
#pragma unroll
        for (int e = 0; e < 8; ++e) {
            int k = unit * 8 + e;
            float v = (k < HW) ? xs[r * HW + k] : 0.f;
            unsigned int uv = __float_as_uint(v);
            unsigned short hi = (unsigned short)(uv >> 16);
            float hif = __uint_as_float(((unsigned int)hi) << 16);
            hv[e] = (short)hi;
            lv[e] = (short)(__float_as_uint(v - hif) >> 16);
        }
        int kb = unit >> 2, lk = unit & 3;
        size_t base = ((((size_t)b * 32 + rb) * 8 + kb) * 4 + lk) * 128 + r * 8;
        *(bf16x8*)(PH + base) = hv;
        *(bf16x8*)(PLo + base) = lv;
    }
}

// ---------------------------------------------------------------------------
// K2: Gram via MFMA — IDENTICAL structure to R8 except the K-loop holds every
// fragment and accumulator in an individually-NAMED register (no ext_vector
// arrays -> no scratch; rule #20). Single-buffered: 16 independent L2 loads
// issued per kb step, then 48 MFMAs; 2 waves/SIMD provide TLP.
// ---------------------------------------------------------------------------
#define MF(A, B, M, N) acc##M##N = __builtin_amdgcn_mfma_f32_16x16x32_bf16(A, B, acc##M##N, 0, 0, 0)

#define MROW(M, AH, AL) \
    MF(AH, bh0, M, 0); MF(AH, bl0, M, 0); MF(AL, bh0, M, 0); \
    MF(AH, bh1, M, 1); MF(AH, bl1, M, 1); MF(AL, bh1, M, 1); \
    MF(AH, bh2, M, 2); MF(AH, bl2, M, 2); MF(AL, bh2, M, 2); \
    MF(AH, bh3, M, 3); MF(AH, bl3, M, 3); MF(AL, bh3, M, 3);

// p* are ushort pointers pre-offset by lane and kb0; rb step = 8*512 = 4096
// ushorts, kb step = 512 ushorts.
#define LD(P, M, C) (*(const bf16x8*)((P) + (M) * 4096 + (C) * 512))

#define KSTEP(C) { \
    bf16x8 ah0 = LD(pAH, 0, C), ah1 = LD(pAH, 1, C), ah2 = LD(pAH, 2, C), ah3 = LD(pAH, 3, C); \
    bf16x8 al0 = LD(pAL, 0, C), al1 = LD(pAL, 1, C), al2 = LD(pAL, 2, C), al3 = LD(pAL, 3, C); \
    bf16x8 bh0 = LD(pBH, 0, C), bh1 = LD(pBH, 1, C), bh2 = LD(pBH, 2, C), bh3 = LD(pBH, 3, C); \
    bf16x8 bl0 = LD(pBL, 0, C), bl1 = LD(pBL, 1, C), bl2 = LD(pBL, 2, C), bl3 = LD(pBL, 3, C); \
    MROW(0, ah0, al0) MROW(1, ah1, al1) MROW(2, ah2, al2) MROW(3, ah3, al3) }

__global__ __launch_bounds__(512, 2) void gram_mfma(
    const unsigned short* __restrict__ PH, const unsigned short* __restrict__ PLo,
    const int* __restrict__ h1, const float* __restrict__ s1,
    const int* __restrict__ h2, const float* __restrict__ s2,
    float* __restrict__ partials)
{
    __shared__ float bins[OUT_DIM];       // 32 KB

    const int bid = blockIdx.x;
    const int xcd = bid & 7;
    const int idx = bid >> 3;             // 0..31
    const int b   = xcd + 8 * (idx & 1);
    const int tile = idx >> 1;            // 0..15
    const int c1b = (tile >> 2) * 128, c2b = (tile & 3) * 128;

    const int t = threadIdx.x;
    const int l = t & 63, w = t >> 6;
    const int half = w >> 2;              // K-half: kb0 = half*4
    const int wr = (w >> 1) & 1, wc = w & 1;

    for (int mm = t; mm < OUT_DIM; mm += 512) bins[mm] = 0.f;

    const int arb = b * 32 + (c1b >> 4) + wr * 4;
    const int brb = b * 32 + (c2b >> 4) + wc * 4;
    const int kb0 = half * 4;
    const int loff = l * 8;

    const unsigned short* pAH = PH  + (size_t)arb * 4096 + kb0 * 512 + loff;
    const unsigned short* pAL = PLo + (size_t)arb * 4096 + kb0 * 512 + loff;
    const unsigned short* pBH = PH  + (size_t)brb * 4096 + kb0 * 512 + loff;
    const unsigned short* pBL = PLo + (size_t)brb * 4096 + kb0 * 512 + loff;

    f32x4 acc00 = {0,0,0,0}, acc01 = {0,0,0,0}, acc02 = {0,0,0,0}, acc03 = {0,0,0,0};
    f32x4 acc10 = {0,0,0,0}, acc11 = {0,0,0,0}, acc12 = {0,0,0,0}, acc13 = {0,0,0,0};
    f32x4 acc20 = {0,0,0,0}, acc21 = {0,0,0,0}, acc22 = {0,0,0,0}, acc23 = {0,0,0,0};
    f32x4 acc30 = {0,0,0,0}, acc31 = {0,0,0,0}, acc32 = {0,0,0,0}, acc33 = {0,0,0,0};

    KSTEP(0)
    KSTEP(1)
    KSTEP(2)
    KSTEP(3)

    // re-materialize for the (cheap) epilogue; constant-indexed after unroll
    const f32x4 accA[4][4] = {{acc00, acc01, acc02, acc03},
                              {acc10, acc11, acc12, acc13},
                              {acc20, acc21, acc22, acc23},
                              {acc30, acc31, acc32, acc33}};

    // C/D layout (verified R3-R8): c2 = col = lane&15, c1 = row = (lane>>4)*4 + reg
    const int lrow = l & 15, lk = l >> 4;
    int   hh1[4][4]; float sv1[4][4];
    int   hh2[4];    float sv2[4];
#pragma unroll
    for (int m = 0; m < 4; ++m)
#pragma unroll
        for (int r = 0; r < 4; ++r) {
            int c1 = c1b + wr * 64 + m * 16 + lk * 4 + r;
            hh1[m][r] = h1[c1]; sv1[m][r] = s1[c1];
        }
#pragma unroll
    for (int n = 0; n < 4; ++n) {
        int c2 = c2b + wc * 64 + n * 16 + lrow;
        hh2[n] = h2[c2]; sv2[n] = s2[c2];
    }

    __syncthreads();                      // bins zeroed; all frag loads done
#pragma unroll
    for (int m = 0; m < 4; ++m)
#pragma unroll
        for (int n = 0; n < 4; ++n)
#pragma unroll
            for (int r = 0; r < 4; ++r) {
                int bin = (hh1[m][r] + hh2[n]) & (OUT_DIM - 1);
                unsafeAtomicAdd(&bins[bin], accA[m][n][r] * sv1[m][r] * sv2[n]);
            }
    __syncthreads();

    float* outp = partials + (size_t)(b * 16 + tile) * OUT_DIM;
    for (int mm = t; mm < OUT_DIM; mm += 512) outp[mm] = bins[mm];
}

// ---------------------------------------------------------------------------
// K3 fin: one block per batch (1024 thr). Reduce 16 slabs, *8192, signed
// sqrt, block-reduce L2 norm, normalize, write out.
// ---------------------------------------------------------------------------
__global__ __launch_bounds__(1024) void fin(
    const float* __restrict__ partials, float* __restrict__ out)
{
    const int b = blockIdx.x, t = threadIdx.x;
    const float* pb = partials + (size_t)b * 16 * OUT_DIM;
    float v[8];
    float sq = 0.f;
#pragma unroll
    for (int i = 0; i < 8; ++i) {
        int k = t + i * 1024;
        float a = 0.f;
#pragma unroll
        for (int tl = 0; tl < 16; ++tl)
            a += pb[tl * OUT_DIM + k];
        a *= (float)OUT_DIM;
        float sg = (a > 0.f) ? 1.f : ((a < 0.f) ? -1.f : 0.f);
        v[i] = sg * sqrtf(fabsf(a) + 1e-5f);
        sq += fabsf(a) + 1e-5f;           // = v[i]^2
    }
#pragma unroll
    for (int off = 32; off; off >>= 1) sq += __shfl_down(sq, off, 64);
    __shared__ float red[16];
    if ((t & 63) == 0) red[t >> 6] = sq;
    __syncthreads();
    float tot = 0.f;
#pragma unroll
    for (int i = 0; i < 16; ++i) tot += red[i];
    float inv = 1.f / fmaxf(sqrtf(tot), 1e-12f);
#pragma unroll
    for (int i = 0; i < 8; ++i)
        out[(size_t)b * OUT_DIM + t + i * 1024] = v[i] * inv;
}

// ---------------------------------------------------------------------------
extern "C" void kernel_launch(void* const* d_in, const int* in_sizes, int n_in,
                              void* d_out, int out_size, void* d_ws, size_t ws_size,
                              hipStream_t stream) {
    const float* x   = (const float*)d_in[0];
    const float* sk1 = (const float*)d_in[1];
    const float* sk2 = (const float*)d_in[2];

    char* ws = (char*)d_ws;
    int*   h1 = (int*)(ws);                              //       0 + 2048
    float* s1 = (float*)(ws + 2048);                     //    2048 + 2048
    int*   h2 = (int*)(ws + 4096);                       //    4096 + 2048
    float* s2 = (float*)(ws + 6144);                     //    6144 + 2048
    float* partials = (float*)(ws + 8192);               // [256][8192] f32 = 8388608
    unsigned short* PH  = (unsigned short*)(ws + 8396800);   // 4 MB
    unsigned short* PLo = (unsigned short*)(ws + 12591104);  // 4 MB -> 16785408 total

    prep<<<1536, 256, 0, stream>>>(x, sk1, sk2, h1, s1, h2, s2, PH, PLo);
    gram_mfma<<<256, 512, 0, stream>>>(PH, PLo, h1, s1, h2, s2, partials);
    fin<<<B_DIM, 1024, 0, stream>>>(partials, (float*)d_out);
}